// Round 10
// baseline (259.580 us; speedup 1.0000x reference)
//
#include <hip/hip_runtime.h>
#include <math.h>

#define BB 8
#define NN 2048
#define FIN 128
#define FOUT 64
#define TI 16
#define TJ 512
#define TJP (TJ + 8)      // +8 bf16 = 16B row pad: A-frag ds_read_b128 bank skew
#define NTILE (NN / TJ)   // 4 j-tiles, one per block (j-split)
#define NW (NN / 32)      // 64 mask words per adjacency row

typedef short bf16x8 __attribute__((ext_vector_type(8)));
typedef float f32x4 __attribute__((ext_vector_type(4)));

// exp(tanh(z)) = exp((u-1)/(u+1)), u = e^{2z}; v_rcp instead of precise div.
__device__ __forceinline__ float exp_tanh(float z) {
    float zc = fminf(fmaxf(z, -15.f), 15.f);
    float u = __expf(zc + zc);
    float tn = (u - 1.f) * __builtin_amdgcn_rcpf(u + 1.f);
    return __expf(tn);
}

__device__ __forceinline__ unsigned short f2bf(float x) {
    union { float f; unsigned u; } v; v.f = x;
    unsigned r = v.u + 0x7FFF + ((v.u >> 16) & 1);   // round-to-nearest-even
    return (unsigned short)(r >> 16);
}

// K1: h = x @ W -> bf16 TRANSPOSED ht[b][c][n]; f1 = h.a1, f2 = h.a2.
__global__ __launch_bounds__(256, 2) void gat_k1(const float* __restrict__ x,
                                                 const float* __restrict__ W,
                                                 const float* __restrict__ a,
                                                 unsigned short* __restrict__ ht,
                                                 float* __restrict__ f1,
                                                 float* __restrict__ f2) {
    __shared__ __attribute__((aligned(16))) float Wl[FIN][FOUT];  // 32 KB
    __shared__ __attribute__((aligned(16))) float xs[16][FIN];    // 8 KB
    int t = threadIdx.x;

    const float4* W4 = (const float4*)W;
    float4* Wl4 = (float4*)&Wl[0][0];
#pragma unroll
    for (int kk = 0; kk < 8; ++kk) Wl4[t + 256 * kk] = W4[t + 256 * kk];

    size_t row0 = (size_t)blockIdx.x * 16;
    const float4* x4 = (const float4*)(x + row0 * FIN);
    float4* xs4 = (float4*)&xs[0][0];
#pragma unroll
    for (int kk = 0; kk < 2; ++kk) xs4[t + 256 * kk] = x4[t + 256 * kk];
    __syncthreads();

    int c = t & 63;
    int rq = t >> 6;
    float acc[4] = {0.f, 0.f, 0.f, 0.f};
#pragma unroll 8
    for (int k = 0; k < FIN; ++k) {
        float wv = Wl[k][c];
        acc[0] = fmaf(xs[rq][k], wv, acc[0]);
        acc[1] = fmaf(xs[rq + 4][k], wv, acc[1]);
        acc[2] = fmaf(xs[rq + 8][k], wv, acc[2]);
        acc[3] = fmaf(xs[rq + 12][k], wv, acc[3]);
    }
    float a1c = a[c], a2c = a[FOUT + c];
#pragma unroll
    for (int m = 0; m < 4; ++m) {
        size_t bn = row0 + rq + 4 * m;
        int b = (int)(bn >> 11);
        int n = (int)(bn & 2047);
        ht[((size_t)b * FOUT + c) * NN + n] = f2bf(acc[m]);
        float p1 = acc[m] * a1c;
        float p2 = acc[m] * a2c;
#pragma unroll
        for (int off = 32; off > 0; off >>= 1) {
            p1 += __shfl_down(p1, off, 64);
            p2 += __shfl_down(p2, off, 64);
        }
        if (c == 0) { f1[bn] = p1; f2[bn] = p2; }
    }
}

// PACK: adj int32 {0,1} -> 1-bit mask. Pure streaming shape (2 KB LDS, tiny
// VGPR, 32 waves/CU, coalesced 16B loads = the m13 6.29 TB/s pattern).
// Converts 134 MB of latency-bound adj traffic inside k2 into one
// BW-bound pass here. Per block: 8192 ints in -> 256 mask words out.
__global__ __launch_bounds__(256) void gat_pack(const int* __restrict__ adj,
                                                unsigned int* __restrict__ adjm) {
    __shared__ __attribute__((aligned(4))) unsigned char nib[2048];
    int t = threadIdx.x;
    const int4* a4 = (const int4*)adj + (size_t)blockIdx.x * 2048;
#pragma unroll
    for (int kk = 0; kk < 8; ++kk) {
        int4 v = a4[t + 256 * kk];
        unsigned n = (unsigned)(v.x > 0) | ((unsigned)(v.y > 0) << 1) |
                     ((unsigned)(v.z > 0) << 2) | ((unsigned)(v.w > 0) << 3);
        nib[t + 256 * kk] = (unsigned char)n;
    }
    __syncthreads();
    const unsigned* nu = (const unsigned*)nib;
    unsigned u0 = nu[2 * t], u1 = nu[2 * t + 1];
    unsigned m = (u0 & 0xFu) | (((u0 >> 8) & 0xFu) << 4) |
                 (((u0 >> 16) & 0xFu) << 8) | (((u0 >> 24) & 0xFu) << 12) |
                 ((u1 & 0xFu) << 16) | (((u1 >> 8) & 0xFu) << 20) |
                 (((u1 >> 16) & 0xFu) << 24) | (((u1 >> 24) & 0xFu) << 28);
    adjm[(size_t)blockIdx.x * 256 + t] = m;
}

// K2: one j-tile per block. R15 delta: adj read via 1-bit mask (4.2 MB total
// instead of 134 MB int32). The mask tile (16 rows x 16 words = 1 KB) is
// cooperatively staged into LDS with one dword/thread, covered by the same
// barrier as f2s/f1s. avreg[8] int4 (32 VGPRs) deleted -> ~60 VGPR body,
// 19.8 KB LDS -> up to 8 blocks/CU. k2 should now be VALU(exp_tanh)/LDS/
// atomic-bound, not adj-latency-bound. Plain (256) launch bound kept (R14).
__global__ __launch_bounds__(256) void gat_k2(const unsigned int* __restrict__ adjm,
                                              const unsigned short* __restrict__ ht,
                                              const float* __restrict__ f1,
                                              const float* __restrict__ f2,
                                              float* __restrict__ accg,
                                              float* __restrict__ rs) {
    __shared__ __attribute__((aligned(16))) unsigned short pb[TI][TJP];  // 16.6 KB
    __shared__ __attribute__((aligned(16))) float f2s[TJ];               // 2 KB
    __shared__ float f1s[TI];
    __shared__ __attribute__((aligned(16))) unsigned int adjms[TI][16];  // 1 KB

    int t = threadIdx.x;
    int i0 = blockIdx.x * TI;
    int j0 = blockIdx.y * TJ;
    int b = blockIdx.z;

    int lane = t & 63;
    int w = t >> 6;         // wave id -> c-tile
    int mrow = lane & 15;   // MFMA m / n index
    int quad = lane >> 4;   // MFMA k-quad

    // p-phase mapping: thread handles j4 = t&127 (float4 group), rows r0+2kk
    int j4 = t & 127;
    int r0 = t >> 7;        // wave-uniform

    // stage mask tile: 16 rows x 16 words = 256 words, one dword per thread
    int arow = t >> 4, awrd = t & 15;
    adjms[arow][awrd] =
        adjm[((size_t)b * NN + i0 + arow) * NW + (j0 >> 5) + awrd];

    // stage this tile's f2 slice (512 floats) + f1s
    ((float2*)f2s)[t] = ((const float2*)(f2 + (size_t)b * NN + j0))[t];
    if (t < TI) f1s[t] = f1[(size_t)b * NN + i0 + t];
    __syncthreads();

    float f1r[8];
    unsigned mrg[8];
#pragma unroll
    for (int kk = 0; kk < 8; ++kk) {
        f1r[kk] = f1s[r0 + 2 * kk];
        // nibble for cols j0+4*j4 .. +3 of row r0+2kk
        mrg[kk] = adjms[r0 + 2 * kk][j4 >> 3] >> ((j4 & 7) * 4);
    }

    // ---- p-phase: mask -> exp(tanh) -> bf16 into LDS ----
    float4 fv = ((const float4*)f2s)[j4];
    float ps[8];
#pragma unroll
    for (int kk = 0; kk < 8; ++kk) {
        unsigned mk = mrg[kk];
        float f1i = f1r[kk];
        float4 p;
        p.x = (mk & 1u) ? exp_tanh(f1i + fv.x) : 0.f;
        p.y = (mk & 2u) ? exp_tanh(f1i + fv.y) : 0.f;
        p.z = (mk & 4u) ? exp_tanh(f1i + fv.z) : 0.f;
        p.w = (mk & 8u) ? exp_tanh(f1i + fv.w) : 0.f;
        ps[kk] = p.x + p.y + p.z + p.w;
        ushort4 pk;
        pk.x = f2bf(p.x); pk.y = f2bf(p.y);
        pk.z = f2bf(p.z); pk.w = f2bf(p.w);
        *(ushort4*)&pb[r0 + 2 * kk][4 * j4] = pk;
    }
    __syncthreads();

    // ---- PV on matrix pipe: 16 chunks of K=32 ----
    const unsigned short* hp =
        ht + ((size_t)b * FOUT + w * 16 + mrow) * NN + j0 + 8 * quad;
    const unsigned short* prow = &pb[mrow][8 * quad];
    f32x4 acc = {0.f, 0.f, 0.f, 0.f};
#pragma unroll 4
    for (int ch = 0; ch < TJ / 32; ++ch) {
        bf16x8 af = *(const bf16x8*)(prow + 32 * ch);
        bf16x8 bf = *(const bf16x8*)(hp + 32 * ch);
        acc = __builtin_amdgcn_mfma_f32_16x16x32_bf16(af, bf, acc, 0, 0, 0);
    }

    // ---- rowsum partials: in-wave reduce then one atomic per (wave,row) ----
#pragma unroll
    for (int kk = 0; kk < 8; ++kk) {
        float s = ps[kk];
#pragma unroll
        for (int off = 32; off > 0; off >>= 1) s += __shfl_down(s, off, 64);
        if (lane == 0)
            atomicAdd(&rs[(size_t)b * NN + i0 + r0 + 2 * kk], s);
    }
    // ---- acc partials: D-frag (col=lane&15, row=quad*4+u) ----
    float* ap = accg + ((size_t)b * NN + i0) * FOUT + w * 16 + mrow;
#pragma unroll
    for (int u = 0; u < 4; ++u) {
        int row = quad * 4 + u;
        atomicAdd(&ap[(size_t)row * FOUT], acc[u]);
    }
}

// K3: out = elu(acc / rowsum), fully coalesced float4.
__global__ __launch_bounds__(256) void gat_k3(const float* __restrict__ accg,
                                              const float* __restrict__ rs,
                                              float* __restrict__ out) {
    int g4 = blockIdx.x * 256 + threadIdx.x;   // float4 index
    int row = g4 >> 4;                         // 16 float4s per 64-col row
    float rinv = __builtin_amdgcn_rcpf(rs[row]);
    float4 v = ((const float4*)accg)[g4];
    float4 o;
    float sx = v.x * rinv; o.x = (sx > 0.f) ? sx : expm1f(sx);
    float sy = v.y * rinv; o.y = (sy > 0.f) ? sy : expm1f(sy);
    float sz = v.z * rinv; o.z = (sz > 0.f) ? sz : expm1f(sz);
    float sw = v.w * rinv; o.w = (sw > 0.f) ? sw : expm1f(sw);
    ((float4*)out)[g4] = o;
}

extern "C" void kernel_launch(void* const* d_in, const int* in_sizes, int n_in,
                              void* d_out, int out_size, void* d_ws, size_t ws_size,
                              hipStream_t stream) {
    const float* x   = (const float*)d_in[0];   // [B,N,128]
    const int*   adj = (const int*)d_in[1];     // [B,N,N]
    const float* W   = (const float*)d_in[2];   // [128,64]
    const float* a   = (const float*)d_in[3];   // [128,1]
    float* out = (float*)d_out;                 // [B,N,64]

    unsigned short* ht = (unsigned short*)d_ws;          // [B][64][2048] bf16, 2.1 MB
    float* f1   = (float*)(ht + (size_t)BB * FOUT * NN); // B*N
    float* f2   = f1 + (size_t)BB * NN;                  // B*N
    float* accg = f2 + (size_t)BB * NN;                  // B*N*64, 4.2 MB
    float* rs   = accg + (size_t)BB * NN * FOUT;         // B*N, 64 KB
    // adjm: prefer workspace; if ws is tight, stage in d_out (exactly
    // B*N*N/32*4 = B*N*64*4 = out_size bytes; d_out is dead until k3, and
    // k2 -- the only adjm reader -- completes before k3 on this stream).
    size_t used = (size_t)BB * FOUT * NN * 2        // ht
                + (size_t)BB * NN * 4 * 2           // f1,f2
                + (size_t)BB * NN * FOUT * 4        // accg
                + (size_t)BB * NN * 4;              // rs
    size_t adjm_bytes = (size_t)BB * NN * (NN / 32) * 4;
    unsigned int* adjm = (ws_size >= used + adjm_bytes)
                             ? (unsigned int*)(rs + (size_t)BB * NN)
                             : (unsigned int*)d_out;
    // zero the atomic accumulators (accg + rs contiguous)
    hipMemsetAsync(accg, 0, ((size_t)BB * NN * FOUT + (size_t)BB * NN) * 4, stream);

    gat_pack<<<dim3((unsigned)((size_t)BB * NN * NN / 8192)), dim3(256), 0, stream>>>(adj, adjm);
    gat_k1<<<dim3(BB * NN / 16), dim3(256), 0, stream>>>(x, W, a, ht, f1, f2);
    gat_k2<<<dim3(NN / TI, NTILE, BB), dim3(256), 0, stream>>>(adjm, ht, f1, f2, accg, rs);
    gat_k3<<<dim3(BB * NN * FOUT / 1024), dim3(256), 0, stream>>>(accg, rs, out);
}

// Round 11
// 227.676 us; speedup vs baseline: 1.1401x; 1.1401x over previous
//
#include <hip/hip_runtime.h>
#include <math.h>

#define BB 8
#define NN 2048
#define FIN 128
#define FOUT 64
#define TI 16
#define TJ 512
#define TJP (TJ + 8)      // +8 bf16 = 16B row pad: A-frag ds_read_b128 bank skew
#define NTILE (NN / TJ)   // 4 j-tiles, looped INSIDE the block (R16: fused)

typedef short bf16x8 __attribute__((ext_vector_type(8)));
typedef float f32x4 __attribute__((ext_vector_type(4)));

// exp(tanh(z)) = exp((u-1)/(u+1)), u = e^{2z}; v_rcp instead of precise div.
__device__ __forceinline__ float exp_tanh(float z) {
    float zc = fminf(fmaxf(z, -15.f), 15.f);
    float u = __expf(zc + zc);
    float tn = (u - 1.f) * __builtin_amdgcn_rcpf(u + 1.f);
    return __expf(tn);
}

__device__ __forceinline__ unsigned short f2bf(float x) {
    union { float f; unsigned u; } v; v.f = x;
    unsigned r = v.u + 0x7FFF + ((v.u >> 16) & 1);   // round-to-nearest-even
    return (unsigned short)(r >> 16);
}

// K1: h = x @ W -> bf16 TRANSPOSED ht[b][c][n]; f1 = h.a1, f2 = h.a2.
// (verbatim from the harness-verified 231.7 us kernel)
__global__ __launch_bounds__(256, 2) void gat_k1(const float* __restrict__ x,
                                                 const float* __restrict__ W,
                                                 const float* __restrict__ a,
                                                 unsigned short* __restrict__ ht,
                                                 float* __restrict__ f1,
                                                 float* __restrict__ f2) {
    __shared__ __attribute__((aligned(16))) float Wl[FIN][FOUT];  // 32 KB
    __shared__ __attribute__((aligned(16))) float xs[16][FIN];    // 8 KB
    int t = threadIdx.x;

    const float4* W4 = (const float4*)W;
    float4* Wl4 = (float4*)&Wl[0][0];
#pragma unroll
    for (int kk = 0; kk < 8; ++kk) Wl4[t + 256 * kk] = W4[t + 256 * kk];

    size_t row0 = (size_t)blockIdx.x * 16;
    const float4* x4 = (const float4*)(x + row0 * FIN);
    float4* xs4 = (float4*)&xs[0][0];
#pragma unroll
    for (int kk = 0; kk < 2; ++kk) xs4[t + 256 * kk] = x4[t + 256 * kk];
    __syncthreads();

    int c = t & 63;
    int rq = t >> 6;
    float acc[4] = {0.f, 0.f, 0.f, 0.f};
#pragma unroll 8
    for (int k = 0; k < FIN; ++k) {
        float wv = Wl[k][c];
        acc[0] = fmaf(xs[rq][k], wv, acc[0]);
        acc[1] = fmaf(xs[rq + 4][k], wv, acc[1]);
        acc[2] = fmaf(xs[rq + 8][k], wv, acc[2]);
        acc[3] = fmaf(xs[rq + 12][k], wv, acc[3]);
    }
    float a1c = a[c], a2c = a[FOUT + c];
#pragma unroll
    for (int m = 0; m < 4; ++m) {
        size_t bn = row0 + rq + 4 * m;
        int b = (int)(bn >> 11);
        int n = (int)(bn & 2047);
        ht[((size_t)b * FOUT + c) * NN + n] = f2bf(acc[m]);
        float p1 = acc[m] * a1c;
        float p2 = acc[m] * a2c;
#pragma unroll
        for (int off = 32; off > 0; off >>= 1) {
            p1 += __shfl_down(p1, off, 64);
            p2 += __shfl_down(p2, off, 64);
        }
        if (c == 0) { f1[bn] = p1; f2[bn] = p2; }
    }
}

// K2f (R16): each block owns TI=16 COMPLETE rows. Loop jt over 4 j-tiles,
// reusing pb/f2s LDS and chaining the MFMA accumulator across iterations.
// Measured falsification (R15): packing adj to bits (-97% k2 traffic) gave
// +28 us total, so k2 is NOT adj-BW-bound -> revert pack, attack the
// accumulation machinery: deletes 4.2M global accg atomics, 131K rs
// atomics, the 4.25 MB memset, and the entire k3 pass. Rowsum reduced
// in-block (shfl + 128 B LDS, no atomics), final elu written directly.
// Hazard note: the loop-top barrier covers pb/f2s WAR -- a wave writes
// pb/f2s only after passing it, which requires ALL waves to have finished
// the previous iteration's MFMA (pb reads) and p-phase (f2s reads).
// Grid 1024 blocks = exactly 4/CU; LDS 18.4 KB; plain (256) bound (R14).
__global__ __launch_bounds__(256) void gat_k2f(const int* __restrict__ adj,
                                               const unsigned short* __restrict__ ht,
                                               const float* __restrict__ f1,
                                               const float* __restrict__ f2,
                                               float* __restrict__ out) {
    __shared__ __attribute__((aligned(16))) unsigned short pb[TI][TJP];  // 16.6 KB
    __shared__ __attribute__((aligned(16))) float f2s[TJ];               // 2 KB
    __shared__ float f1s[TI];
    __shared__ float rsw[2][TI];                                         // 128 B

    int t = threadIdx.x;
    int i0 = blockIdx.x * TI;
    int b = blockIdx.y;

    int lane = t & 63;
    int w = t >> 6;         // wave id -> c-tile
    int mrow = lane & 15;   // MFMA m / n index
    int quad = lane >> 4;   // MFMA k-quad

    // p-phase mapping: thread handles j4 = t&127 (float4 group), rows r0+2kk
    int j4 = t & 127;
    int r0 = t >> 7;        // wave-uniform

    if (t < TI) f1s[t] = f1[(size_t)b * NN + i0 + t];
    __syncthreads();

    float f1r[8];
    float ps[8];
#pragma unroll
    for (int kk = 0; kk < 8; ++kk) {
        f1r[kk] = f1s[r0 + 2 * kk];
        ps[kk] = 0.f;
    }
    f32x4 acc = {0.f, 0.f, 0.f, 0.f};

    for (int jt = 0; jt < NTILE; ++jt) {
        int j0 = jt * TJ;

        // adj loads issue immediately (cover with f2s staging + barrier)
        const int* adjbase = adj + (((size_t)b * NN + i0) * NN) + j0 + 4 * j4;
        int4 avreg[8];
#pragma unroll
        for (int kk = 0; kk < 8; ++kk)
            avreg[kk] = *(const int4*)(adjbase + (size_t)(r0 + 2 * kk) * NN);

        // stage this j-tile's f2 slice (512 floats)
        ((float2*)f2s)[t] = ((const float2*)(f2 + (size_t)b * NN + j0))[t];
        __syncthreads();   // also the WAR barrier for pb/f2s reuse

        // ---- p-phase: mask -> exp(tanh) -> bf16 into LDS ----
        float4 fv = ((const float4*)f2s)[j4];
#pragma unroll
        for (int kk = 0; kk < 8; ++kk) {
            int4 av = avreg[kk];
            float f1i = f1r[kk];
            float4 p;
            p.x = (av.x > 0) ? exp_tanh(f1i + fv.x) : 0.f;
            p.y = (av.y > 0) ? exp_tanh(f1i + fv.y) : 0.f;
            p.z = (av.z > 0) ? exp_tanh(f1i + fv.z) : 0.f;
            p.w = (av.w > 0) ? exp_tanh(f1i + fv.w) : 0.f;
            ps[kk] += p.x + p.y + p.z + p.w;   // running rowsum across jt
            ushort4 pk;
            pk.x = f2bf(p.x); pk.y = f2bf(p.y);
            pk.z = f2bf(p.z); pk.w = f2bf(p.w);
            *(ushort4*)&pb[r0 + 2 * kk][4 * j4] = pk;
        }
        __syncthreads();

        // ---- PV on matrix pipe: 16 chunks of K=32, acc chained over jt ----
        const unsigned short* hp =
            ht + ((size_t)b * FOUT + w * 16 + mrow) * NN + j0 + 8 * quad;
        const unsigned short* prow = &pb[mrow][8 * quad];
#pragma unroll 4
        for (int ch = 0; ch < TJ / 32; ++ch) {
            bf16x8 af = *(const bf16x8*)(prow + 32 * ch);
            bf16x8 bf = *(const bf16x8*)(hp + 32 * ch);
            acc = __builtin_amdgcn_mfma_f32_16x16x32_bf16(af, bf, acc, 0, 0, 0);
        }
    }

    // ---- rowsum: in-wave shfl reduce, 2 wave-partials per row via LDS ----
    // wave w covers rows r0=w>>1 parity; slot w&1 -> each (slot,row) written once
#pragma unroll
    for (int kk = 0; kk < 8; ++kk) {
        float s = ps[kk];
#pragma unroll
        for (int off = 32; off > 0; off >>= 1) s += __shfl_down(s, off, 64);
        if (lane == 0) rsw[w & 1][r0 + 2 * kk] = s;
    }
    __syncthreads();

    // ---- epilogue: final out = elu(acc / rowsum), D-frag mapping verified ----
    float* op = out + ((size_t)b * NN + i0) * FOUT + w * 16 + mrow;
#pragma unroll
    for (int u = 0; u < 4; ++u) {
        int row = quad * 4 + u;
        float rinv = __builtin_amdgcn_rcpf(rsw[0][row] + rsw[1][row]);
        float sx = acc[u] * rinv;
        op[(size_t)row * FOUT] = (sx > 0.f) ? sx : expm1f(sx);
    }
}

extern "C" void kernel_launch(void* const* d_in, const int* in_sizes, int n_in,
                              void* d_out, int out_size, void* d_ws, size_t ws_size,
                              hipStream_t stream) {
    const float* x   = (const float*)d_in[0];   // [B,N,128]
    const int*   adj = (const int*)d_in[1];     // [B,N,N]
    const float* W   = (const float*)d_in[2];   // [128,64]
    const float* a   = (const float*)d_in[3];   // [128,1]
    float* out = (float*)d_out;                 // [B,N,64]

    unsigned short* ht = (unsigned short*)d_ws;          // [B][64][2048] bf16, 2.1 MB
    float* f1   = (float*)(ht + (size_t)BB * FOUT * NN); // B*N
    float* f2   = f1 + (size_t)BB * NN;                  // B*N
    // total ws use: 2.23 MB (well under the 6.52 MB the baseline verified)

    gat_k1<<<dim3(BB * NN / 16), dim3(256), 0, stream>>>(x, W, a, ht, f1, f2);
    gat_k2f<<<dim3(NN / TI, BB), dim3(256), 0, stream>>>(adj, ht, f1, f2, out);
}